// Round 5
// baseline (442.379 us; speedup 1.0000x reference)
//
#include <hip/hip_runtime.h>
#include <hip/hip_bf16.h>
#include <math.h>

typedef __hip_bfloat16 bf16;
typedef __attribute__((ext_vector_type(8))) short bf16x8;
typedef __attribute__((ext_vector_type(4))) float f32x4;

#define B_  2
#define T_  2048
#define C_  2048
#define H_  16
#define HS_ 128
#define DL_ 1024
#define M_  (B_ * T_)   // 4096 tokens
#define NT64_ 32        // 32 q-tiles of 64 rows per (b,h)

// async global->LDS, 16 B per lane. LDS dest is wave-uniform base + lane*16.
__device__ inline void lds16(const bf16* g, bf16* l) {
    __builtin_amdgcn_global_load_lds(
        (const __attribute__((address_space(1))) void*)g,
        (__attribute__((address_space(3))) void*)l, 16, 0, 0);
}

// ---------------------------------------------------------------------------
// fp32 -> bf16 cast, 8 elems/thread
// ---------------------------------------------------------------------------
__global__ __launch_bounds__(256) void cast_bf16_k(
    const float* __restrict__ in, bf16* __restrict__ out)
{
    const size_t i = ((size_t)blockIdx.x * 256 + threadIdx.x) * 8;
    const float4 a = *(const float4*)(in + i);
    const float4 b = *(const float4*)(in + i + 4);
    bf16 o[8];
    o[0] = __float2bfloat16(a.x); o[1] = __float2bfloat16(a.y);
    o[2] = __float2bfloat16(a.z); o[3] = __float2bfloat16(a.w);
    o[4] = __float2bfloat16(b.x); o[5] = __float2bfloat16(b.y);
    o[6] = __float2bfloat16(b.z); o[7] = __float2bfloat16(b.w);
    *(uint4*)(out + i) = *(const uint4*)o;
}

// ---------------------------------------------------------------------------
// Fused transpose+cast of all 5 weights: blockIdx.z selects the matrix.
// ---------------------------------------------------------------------------
__global__ __launch_bounds__(256) void transpose_cast5(
    const float* __restrict__ s0, const float* __restrict__ s1,
    const float* __restrict__ s2, const float* __restrict__ s3,
    const float* __restrict__ s4,
    bf16* __restrict__ d0, bf16* __restrict__ d1, bf16* __restrict__ d2,
    bf16* __restrict__ d3, bf16* __restrict__ d4)
{
    const float* in; bf16* out; int R, Cc;
    switch (blockIdx.z) {
        case 0: in = s0; out = d0; R = C_;  Cc = C_;  break;  // Wq (C,C)
        case 1: in = s1; out = d1; R = C_;  Cc = DL_; break;  // Wc (C,DL)
        case 2: in = s2; out = d2; R = DL_; Cc = C_;  break;  // Wk (DL,C)
        case 3: in = s3; out = d3; R = DL_; Cc = C_;  break;  // Wv (DL,C)
        default: in = s4; out = d4; R = C_; Cc = C_;  break;  // Wo (C,C)
    }
    const int bx = blockIdx.x * 32, by = blockIdx.y * 32;
    if (bx >= Cc || by >= R) return;
    __shared__ float t[32][33];
    const int tx = threadIdx.x & 31, ty = threadIdx.x >> 5;
#pragma unroll
    for (int i = 0; i < 32; i += 8)
        t[ty + i][tx] = in[(size_t)(by + ty + i) * Cc + bx + tx];
    __syncthreads();
#pragma unroll
    for (int i = 0; i < 32; i += 8)
        out[(size_t)(bx + ty + i) * R + by + tx] = __float2bfloat16(t[tx][ty + i]);
}

// ---------------------------------------------------------------------------
// 256x128-tile MFMA GEMM core, 512 threads = 8 waves (4x2), BK=64,
// 3-buffer LDS ring (48 KB/buf = 144 KB), counted vmcnt(6), ONE barrier
// per K-tile. EXACT R2 core (measured best: qc=69.9us, 0 bank conflicts).
// ---------------------------------------------------------------------------
#define GEMM250_CORE(A_, Bt_, ldA_, ldB_, Kdim_)                               \
    __shared__ __align__(16) bf16 smem[3 * 24576];   /* 144 KB */              \
    const int tid  = threadIdx.x;                                              \
    const int lane = tid & 63;                                                 \
    const int wid  = tid >> 6;                       /* 0..7 */                \
    const int wr   = wid >> 1, wc = wid & 1;         /* 4x2 waves */           \
    const int quad = lane >> 4, l16 = lane & 15;                               \
    const int sw8  = (l16 >> 1) & 7;                                           \
    f32x4 acc[4][4];                                                           \
    _Pragma("unroll")                                                          \
    for (int i = 0; i < 4; i++)                                                \
        _Pragma("unroll")                                                      \
        for (int j = 0; j < 4; j++) acc[i][j] = (f32x4){0.f, 0.f, 0.f, 0.f};   \
    const int sr  = tid >> 3;                        /* 0..63 */               \
    const int ssl = ((tid & 7) ^ ((sr >> 1) & 7)) * 8;                         \
    const bf16* pa = (A_)  + (size_t)(m0 + sr) * (ldA_) + ssl;                 \
    const bf16* pb = (Bt_) + (size_t)(n0 + sr) * (ldB_) + ssl;                 \
    const size_t a64 = (size_t)64 * (ldA_), b64 = (size_t)64 * (ldB_);         \
    const int NT = (Kdim_) / 64;                                               \
    _Pragma("unroll")                                                          \
    for (int pt = 0; pt < 2; ++pt) {             /* prologue: tiles 0,1 */     \
        bf16* dst = smem + pt * 24576 + tid * 8;                               \
        const size_t ko = (size_t)pt * 64;                                     \
        lds16(pa + ko,           dst);                                         \
        lds16(pa + a64 + ko,     dst + 4096);                                  \
        lds16(pa + 2*a64 + ko,   dst + 8192);                                  \
        lds16(pa + 3*a64 + ko,   dst + 12288);                                 \
        lds16(pb + ko,           dst + 16384);                                 \
        lds16(pb + b64 + ko,     dst + 20480);                                 \
    }                                                                          \
    int cur = 0, nxt2 = 2;                                                     \
    for (int t = 0; t < NT; ++t) {                                             \
        if (t == NT - 1) {                                                     \
            __asm__ __volatile__("s_waitcnt vmcnt(0)" ::: "memory");           \
        } else {                                                               \
            __asm__ __volatile__("s_waitcnt vmcnt(6)" ::: "memory");           \
        }                                                                      \
        __builtin_amdgcn_s_barrier();                                          \
        __builtin_amdgcn_sched_barrier(0);                                     \
        if (t + 2 < NT) {                                                      \
            bf16* dst = smem + nxt2 * 24576 + tid * 8;                         \
            const size_t ko = (size_t)(t + 2) * 64;                            \
            lds16(pa + ko,           dst);                                     \
            lds16(pa + a64 + ko,     dst + 4096);                              \
            lds16(pa + 2*a64 + ko,   dst + 8192);                              \
            lds16(pa + 3*a64 + ko,   dst + 12288);                             \
            lds16(pb + ko,           dst + 16384);                             \
            lds16(pb + b64 + ko,     dst + 20480);                             \
        }                                                                      \
        const bf16* Ab = smem + cur * 24576;                                   \
        const bf16* Bb = Ab + 16384;                                           \
        bf16x8 af[4][2], bfr[4][2];                                            \
        _Pragma("unroll")                                                      \
        for (int mi = 0; mi < 4; mi++)                                         \
            _Pragma("unroll")                                                  \
            for (int ks = 0; ks < 2; ks++)                                     \
                af[mi][ks] = *(const bf16x8*)&Ab[(wr*64 + mi*16 + l16)*64 +    \
                                                 (((ks<<2)|quad) ^ sw8)*8];    \
        _Pragma("unroll")                                                      \
        for (int ni = 0; ni < 4; ni++)                                         \
            _Pragma("unroll")                                                  \
            for (int ks = 0; ks < 2; ks++)                                     \
                bfr[ni][ks] = *(const bf16x8*)&Bb[(wc*64 + ni*16 + l16)*64 +   \
                                                  (((ks<<2)|quad) ^ sw8)*8];   \
        __builtin_amdgcn_s_setprio(1);                                         \
        _Pragma("unroll")                                                      \
        for (int ks = 0; ks < 2; ks++)                                         \
            _Pragma("unroll")                                                  \
            for (int mi = 0; mi < 4; mi++)                                     \
                _Pragma("unroll")                                              \
                for (int ni = 0; ni < 4; ni++)                                 \
                    acc[mi][ni] = __builtin_amdgcn_mfma_f32_16x16x32_bf16(     \
                        af[mi][ks], bfr[ni][ks], acc[mi][ni], 0, 0, 0);        \
        __builtin_amdgcn_s_setprio(0);                                         \
        cur  = (cur  == 2) ? 0 : cur  + 1;                                     \
        nxt2 = (nxt2 == 2) ? 0 : nxt2 + 1;                                     \
    }

// ---------------------------------------------------------------------------
// Fused Q+C projection: [q | clat] = x @ [Wq | Wc], N=3072. 384 blocks.
// ---------------------------------------------------------------------------
__global__ __launch_bounds__(512, 2) void gemm_qc_250(
    const bf16* __restrict__ A, const bf16* __restrict__ Bt,
    bf16* __restrict__ Cq, bf16* __restrict__ Cc)
{
    const int m0 = blockIdx.y * 256, n0 = blockIdx.x * 128;
    GEMM250_CORE(A, Bt, C_, C_, C_)
    const bool is_q = (n0 < C_);                       // 128 | 2048: uniform
    const float scl = is_q ? 0.08838834764831845f : 1.0f;   // 1/sqrt(128)
    bf16* dst = is_q ? Cq : Cc;
    const int ld   = is_q ? C_ : DL_;
    const int coff = is_q ? 0 : C_;
#pragma unroll
    for (int mi = 0; mi < 4; mi++) {
#pragma unroll
        for (int ni = 0; ni < 4; ni++) {
            const int col = n0 - coff + wc * 64 + ni * 16 + l16;
#pragma unroll
            for (int r = 0; r < 4; r++) {
                const int row = m0 + wr * 64 + mi * 16 + quad * 4 + r;
                dst[(size_t)row * ld + col] = __float2bfloat16(acc[mi][ni][r] * scl);
            }
        }
    }
}

// ---------------------------------------------------------------------------
// Fused K-proj + Vt-proj (both K=1024, both consume clat): 512 blocks.
// ---------------------------------------------------------------------------
__global__ __launch_bounds__(512, 2) void gemm_kv_250(
    const bf16* __restrict__ clat, const bf16* __restrict__ Wk_t,
    const bf16* __restrict__ Wv_t, bf16* __restrict__ kk, bf16* __restrict__ vt)
{
    const int bid = blockIdx.x;
    const bf16 *A, *Bt; bf16* dst; int N, m0, n0;
    if (bid < 256) { A = clat; Bt = Wk_t; dst = kk; N = C_;
                     m0 = (bid >> 4) * 256; n0 = (bid & 15) * 128; }
    else           { const int t2 = bid - 256;
                     A = Wv_t; Bt = clat; dst = vt; N = M_;
                     m0 = (t2 >> 5) * 256; n0 = (t2 & 31) * 128; }
    GEMM250_CORE(A, Bt, DL_, DL_, DL_)
#pragma unroll
    for (int mi = 0; mi < 4; mi++) {
#pragma unroll
        for (int ni = 0; ni < 4; ni++) {
            const int col = n0 + wc * 64 + ni * 16 + l16;
#pragma unroll
            for (int r = 0; r < 4; r++) {
                const int row = m0 + wr * 64 + mi * 16 + quad * 4 + r;
                dst[(size_t)row * N + col] = __float2bfloat16(acc[mi][ni][r]);
            }
        }
    }
}

// ---------------------------------------------------------------------------
// Out-projection: out = y @ Wo_t^T + bo, fp32 out. 256 blocks (one round).
// ---------------------------------------------------------------------------
__global__ __launch_bounds__(512, 2) void gemm_out_250(
    const bf16* __restrict__ A, const bf16* __restrict__ Bt,
    float* __restrict__ Cf32, const float* __restrict__ bias)
{
    const int m0 = blockIdx.y * 256, n0 = blockIdx.x * 128;
    GEMM250_CORE(A, Bt, C_, C_, C_)
#pragma unroll
    for (int mi = 0; mi < 4; mi++) {
#pragma unroll
        for (int ni = 0; ni < 4; ni++) {
            const int col = n0 + wc * 64 + ni * 16 + l16;
#pragma unroll
            for (int r = 0; r < 4; r++) {
                const int row = m0 + wr * 64 + mi * 16 + quad * 4 + r;
                Cf32[(size_t)row * C_ + col] = acc[mi][ni][r] + bias[col];
            }
        }
    }
}

// ---------------------------------------------------------------------------
// Flash attention v2: single q-tile (64 rows) per block, 256 thr = 4 waves,
// grid 1024. K staged in LDS (dbuf, shared by 4 waves); V read DIRECTLY from
// global — per-(b,h) V is 512 KB and all same-bh blocks sit on one XCD
// (bid&7 invariant), so V is L2-resident (m169 lesson: don't stage what
// cache-fits). LDS = Ks 32 KB + Ps 9 KB = 41 KB -> 3 blocks/CU, 12 waves/CU
// (+50% TLP vs dual-tile's 8). LPT dispatch: longest blocks (pa=31) first.
// Numerics bitwise-identical to flash_dual (same accumulation order).
// ---------------------------------------------------------------------------
__global__ __launch_bounds__(256, 3) void flash_v(
    const bf16* __restrict__ Q, const bf16* __restrict__ K,
    const bf16* __restrict__ Vt, bf16* __restrict__ Y)
{
    __shared__ __align__(16) bf16 Ks[2][4][64][32];    // 32 KB (dbuf)
    __shared__ __align__(16) bf16 Ps[4][16][72];       // 9 KB (+8 pad)
    const int tid  = threadIdx.x;
    const int lane = tid & 63, wv = tid >> 6;          // wv 0..3
    const int quad = lane >> 4, l16 = lane & 15;
    const int sw = (l16 >> 1) & 3;
    const int bid = blockIdx.x;
    const int bh = (bid & 7) * 4 + ((bid >> 3) & 3);   // XCD-local (b,h)
    const int pa = (NT64_ - 1) - (bid >> 5);           // LPT: longest first
    const int b = bh >> 4, h = bh & 15;
    const int q0 = pa * 64;
    const int nj = pa + 1;                             // kv tiles (causal)
    const int rb = q0 + wv * 16;                       // wave's row base

    // K staging: 256 threads cover 16 KB -> 4 lds16 each
    const int sr  = tid >> 2;                          // row 0..63
    const int ssl = ((tid & 3) ^ ((sr >> 1) & 3)) * 8; // swizzled 16B slot

    // Q fragments: wave rows q0 + wv*16 + l16, 4 k-chunks
    bf16x8 qf[4];
    {
        const size_t rQ = (size_t)(b * T_ + q0 + wv * 16 + l16) * C_ + h * HS_;
#pragma unroll
        for (int c = 0; c < 4; c++)
            qf[c] = *(const bf16x8*)(Q + rQ + c * 32 + quad * 8);
    }
    // V direct-read row base: lane reads hs row (dt*16+l16), kv chunk quad*8
    const bf16* vrow = Vt + (size_t)(h * HS_ + l16) * M_ + b * T_ + quad * 8;

    f32x4 o[8];
#pragma unroll
    for (int dt = 0; dt < 8; dt++) o[dt] = (f32x4){0.f, 0.f, 0.f, 0.f};
    float l_s[4] = {0.f, 0.f, 0.f, 0.f};

    auto stageK = [&](int j, int sbuf) {
        const int kv0 = j * 64;
#pragma unroll
        for (int kc = 0; kc < 4; kc++)
            lds16(K + (size_t)(b * T_ + kv0 + sr) * C_ + h * HS_ + kc * 32 + ssl,
                  &Ks[sbuf][kc][0][0] + tid * 8);
    };

    // softmax + Ps store for one 32-kv half (nt0 in {0,2}); returns PV A-frag.
    auto sm_half = [&](const f32x4* s, int nt0, bool diag, int kv0) {
        float p[2][4];
#pragma unroll
        for (int t = 0; t < 2; t++)
#pragma unroll
            for (int r = 0; r < 4; r++) {
                const int nt = nt0 + t;
                float e = __expf(s[nt][r]);
                if (diag) {
                    const int col = kv0 + nt * 16 + l16;
                    const int row = rb + quad * 4 + r;
                    if (col > row) e = 0.f;
                }
                p[t][r] = e;
            }
#pragma unroll
        for (int r = 0; r < 4; r++) l_s[r] += p[0][r] + p[1][r];
#pragma unroll
        for (int t = 0; t < 2; t++)
#pragma unroll
            for (int r = 0; r < 4; r++)
                Ps[wv][quad * 4 + r][(nt0 + t) * 16 + l16] = __float2bfloat16(p[t][r]);
        return *(const bf16x8*)&Ps[wv][l16][nt0 * 16 + quad * 8];
    };

    stageK(0, 0);
    for (int j = 0; j < nj; j++) {
        const int kv0 = j * 64;
        if (j + 1 < nj) {
            stageK(j + 1, (j + 1) & 1);
            __asm__ __volatile__("s_waitcnt vmcnt(4)" ::: "memory");   // tile j landed
        } else {
            __asm__ __volatile__("s_waitcnt vmcnt(0)" ::: "memory");
        }
        __builtin_amdgcn_s_barrier();
        const int buf = j & 1;

        f32x4 s[4];
#pragma unroll
        for (int nt = 0; nt < 4; nt++) s[nt] = (f32x4){0.f, 0.f, 0.f, 0.f};
        __builtin_amdgcn_s_setprio(1);
#pragma unroll
        for (int c = 0; c < 4; c++) {
            bf16x8 kf[4];
#pragma unroll
            for (int nt = 0; nt < 4; nt++)
                kf[nt] = *(const bf16x8*)&Ks[buf][c][nt * 16 + l16][(quad ^ sw) * 8];
#pragma unroll
            for (int nt = 0; nt < 4; nt++)
                s[nt] = __builtin_amdgcn_mfma_f32_16x16x32_bf16(qf[c], kf[nt], s[nt], 0, 0, 0);
        }
        __builtin_amdgcn_s_setprio(0);

        const bool dg = (j == nj - 1);                 // diagonal tile
        const bf16x8 p0 = sm_half(s, 0, dg, kv0);
        const bf16x8 p1 = sm_half(s, 2, dg, kv0);

        __builtin_amdgcn_s_setprio(1);
#pragma unroll
        for (int dt = 0; dt < 8; dt++) {
            const bf16x8 vf0 = *(const bf16x8*)(vrow + (size_t)(dt * 16) * M_ + kv0);
            o[dt] = __builtin_amdgcn_mfma_f32_16x16x32_bf16(p0, vf0, o[dt], 0, 0, 0);
        }
#pragma unroll
        for (int dt = 0; dt < 8; dt++) {
            const bf16x8 vf1 = *(const bf16x8*)(vrow + (size_t)(dt * 16) * M_ + kv0 + 32);
            o[dt] = __builtin_amdgcn_mfma_f32_16x16x32_bf16(p1, vf1, o[dt], 0, 0, 0);
        }
        __builtin_amdgcn_s_setprio(0);
        __asm__ __volatile__("s_waitcnt lgkmcnt(0)" ::: "memory");     // kf reads done
        __builtin_amdgcn_s_barrier();                  // buf free for stage j+2
    }

    // ---- epilogue: reduce l across 16-lane col group, normalize, store
    {
        float inv[4];
#pragma unroll
        for (int r = 0; r < 4; r++) {
            float l = l_s[r];
            l += __shfl_xor(l, 1);
            l += __shfl_xor(l, 2);
            l += __shfl_xor(l, 4);
            l += __shfl_xor(l, 8);
            inv[r] = 1.f / l;
        }
#pragma unroll
        for (int dt = 0; dt < 8; dt++)
#pragma unroll
            for (int r = 0; r < 4; r++)
                Y[(size_t)(b * T_ + rb + quad * 4 + r) * C_ + h * HS_ + dt * 16 + l16] =
                    __float2bfloat16(o[dt][r] * inv[r]);
    }
}

// ---------------------------------------------------------------------------
extern "C" void kernel_launch(void* const* d_in, const int* in_sizes, int n_in,
                              void* d_out, int out_size, void* d_ws, size_t ws_size,
                              hipStream_t stream) {
    const float* x  = (const float*)d_in[0];
    const float* Wq = (const float*)d_in[1];
    const float* Wc = (const float*)d_in[2];
    const float* Wk = (const float*)d_in[3];
    const float* Wv = (const float*)d_in[4];
    const float* Wo = (const float*)d_in[5];
    const float* bo = (const float*)d_in[6];
    float* out = (float*)d_out;

    bf16* ws   = (bf16*)d_ws;
    bf16* x_bf = ws;                            // (M,C)
    bf16* Wq_t = x_bf + (size_t)M_ * C_;        // (C,C)   contiguous with Wc_t
    bf16* Wc_t = Wq_t + (size_t)C_ * C_;        // (DL,C)
    bf16* Wk_t = Wc_t + (size_t)DL_ * C_;       // (C,DL)
    bf16* Wv_t = Wk_t + (size_t)C_ * DL_;       // (C,DL)
    bf16* Wo_t = Wv_t + (size_t)C_ * DL_;       // (C,C)
    bf16* q    = Wo_t + (size_t)C_ * C_;        // (M,C)  pre-scaled by 1/sqrt(HS)
    bf16* clat = q    + (size_t)M_ * C_;        // (M,DL)
    bf16* kk   = clat + (size_t)M_ * DL_;       // (M,C)
    bf16* vt   = kk   + (size_t)M_ * C_;        // (C,M)  V transposed
    bf16* y    = vt   + (size_t)C_ * M_;        // (M,C)

    const dim3 blk(256);
    const dim3 blk512(512);

    cast_bf16_k<<<dim3((M_ * C_) / (256 * 8)), blk, 0, stream>>>(x, x_bf);
    transpose_cast5<<<dim3(C_ / 32, C_ / 32, 5), blk, 0, stream>>>(
        Wq, Wc, Wk, Wv, Wo, Wq_t, Wc_t, Wk_t, Wv_t, Wo_t);

    // fused [q | clat] projection: Bt = [Wq_t ; Wc_t] (3072 x 2048)
    gemm_qc_250<<<dim3((C_ + DL_) / 128, M_ / 256), blk512, 0, stream>>>(
        x_bf, Wq_t, q, clat);
    // fused K-proj + Vt-proj (512 blocks, both K=1024)
    gemm_kv_250<<<dim3(512), blk512, 0, stream>>>(clat, Wk_t, Wv_t, kk, vt);

    flash_v<<<dim3(NT64_ * H_ * B_), blk, 0, stream>>>(q, kk, vt, y);

    gemm_out_250<<<dim3(C_ / 128, M_ / 256), blk512, 0, stream>>>(
        y, Wo_t, out, bo);
}

// Round 7
// 329.096 us; speedup vs baseline: 1.3442x; 1.3442x over previous
//
#include <hip/hip_runtime.h>
#include <hip/hip_bf16.h>
#include <math.h>

typedef __hip_bfloat16 bf16;
typedef __attribute__((ext_vector_type(8))) short bf16x8;
typedef __attribute__((ext_vector_type(4))) float f32x4;

#define B_  2
#define T_  2048
#define C_  2048
#define H_  16
#define HS_ 128
#define DL_ 1024
#define M_  (B_ * T_)   // 4096 tokens
#define NT64_ 32        // 32 q-tiles of 64 rows per (b,h)

// async global->LDS, 16 B per lane. LDS dest is wave-uniform base + lane*16.
__device__ inline void lds16(const bf16* g, bf16* l) {
    __builtin_amdgcn_global_load_lds(
        (const __attribute__((address_space(1))) void*)g,
        (__attribute__((address_space(3))) void*)l, 16, 0, 0);
}

// ---------------------------------------------------------------------------
// fp32 -> bf16 cast, 8 elems/thread
// ---------------------------------------------------------------------------
__global__ __launch_bounds__(256) void cast_bf16_k(
    const float* __restrict__ in, bf16* __restrict__ out)
{
    const size_t i = ((size_t)blockIdx.x * 256 + threadIdx.x) * 8;
    const float4 a = *(const float4*)(in + i);
    const float4 b = *(const float4*)(in + i + 4);
    bf16 o[8];
    o[0] = __float2bfloat16(a.x); o[1] = __float2bfloat16(a.y);
    o[2] = __float2bfloat16(a.z); o[3] = __float2bfloat16(a.w);
    o[4] = __float2bfloat16(b.x); o[5] = __float2bfloat16(b.y);
    o[6] = __float2bfloat16(b.z); o[7] = __float2bfloat16(b.w);
    *(uint4*)(out + i) = *(const uint4*)o;
}

// ---------------------------------------------------------------------------
// Fused transpose+cast of all 5 weights: blockIdx.z selects the matrix.
// ---------------------------------------------------------------------------
__global__ __launch_bounds__(256) void transpose_cast5(
    const float* __restrict__ s0, const float* __restrict__ s1,
    const float* __restrict__ s2, const float* __restrict__ s3,
    const float* __restrict__ s4,
    bf16* __restrict__ d0, bf16* __restrict__ d1, bf16* __restrict__ d2,
    bf16* __restrict__ d3, bf16* __restrict__ d4)
{
    const float* in; bf16* out; int R, Cc;
    switch (blockIdx.z) {
        case 0: in = s0; out = d0; R = C_;  Cc = C_;  break;  // Wq (C,C)
        case 1: in = s1; out = d1; R = C_;  Cc = DL_; break;  // Wc (C,DL)
        case 2: in = s2; out = d2; R = DL_; Cc = C_;  break;  // Wk (DL,C)
        case 3: in = s3; out = d3; R = DL_; Cc = C_;  break;  // Wv (DL,C)
        default: in = s4; out = d4; R = C_; Cc = C_;  break;  // Wo (C,C)
    }
    const int bx = blockIdx.x * 32, by = blockIdx.y * 32;
    if (bx >= Cc || by >= R) return;
    __shared__ float t[32][33];
    const int tx = threadIdx.x & 31, ty = threadIdx.x >> 5;
#pragma unroll
    for (int i = 0; i < 32; i += 8)
        t[ty + i][tx] = in[(size_t)(by + ty + i) * Cc + bx + tx];
    __syncthreads();
#pragma unroll
    for (int i = 0; i < 32; i += 8)
        out[(size_t)(bx + ty + i) * R + by + tx] = __float2bfloat16(t[tx][ty + i]);
}

// ---------------------------------------------------------------------------
// 256x128-tile MFMA GEMM core, 512 threads = 8 waves (4x2), BK=64,
// 3-buffer LDS ring (48 KB/buf = 144 KB), counted vmcnt(6), ONE barrier
// per K-tile. EXACT R2 core (measured best: qc=69.9us, 0 bank conflicts).
// ---------------------------------------------------------------------------
#define GEMM250_CORE(A_, Bt_, ldA_, ldB_, Kdim_)                               \
    __shared__ __align__(16) bf16 smem[3 * 24576];   /* 144 KB */              \
    const int tid  = threadIdx.x;                                              \
    const int lane = tid & 63;                                                 \
    const int wid  = tid >> 6;                       /* 0..7 */                \
    const int wr   = wid >> 1, wc = wid & 1;         /* 4x2 waves */           \
    const int quad = lane >> 4, l16 = lane & 15;                               \
    const int sw8  = (l16 >> 1) & 7;                                           \
    f32x4 acc[4][4];                                                           \
    _Pragma("unroll")                                                          \
    for (int i = 0; i < 4; i++)                                                \
        _Pragma("unroll")                                                      \
        for (int j = 0; j < 4; j++) acc[i][j] = (f32x4){0.f, 0.f, 0.f, 0.f};   \
    const int sr  = tid >> 3;                        /* 0..63 */               \
    const int ssl = ((tid & 7) ^ ((sr >> 1) & 7)) * 8;                         \
    const bf16* pa = (A_)  + (size_t)(m0 + sr) * (ldA_) + ssl;                 \
    const bf16* pb = (Bt_) + (size_t)(n0 + sr) * (ldB_) + ssl;                 \
    const size_t a64 = (size_t)64 * (ldA_), b64 = (size_t)64 * (ldB_);         \
    const int NT = (Kdim_) / 64;                                               \
    _Pragma("unroll")                                                          \
    for (int pt = 0; pt < 2; ++pt) {             /* prologue: tiles 0,1 */     \
        bf16* dst = smem + pt * 24576 + tid * 8;                               \
        const size_t ko = (size_t)pt * 64;                                     \
        lds16(pa + ko,           dst);                                         \
        lds16(pa + a64 + ko,     dst + 4096);                                  \
        lds16(pa + 2*a64 + ko,   dst + 8192);                                  \
        lds16(pa + 3*a64 + ko,   dst + 12288);                                 \
        lds16(pb + ko,           dst + 16384);                                 \
        lds16(pb + b64 + ko,     dst + 20480);                                 \
    }                                                                          \
    int cur = 0, nxt2 = 2;                                                     \
    for (int t = 0; t < NT; ++t) {                                             \
        if (t == NT - 1) {                                                     \
            __asm__ __volatile__("s_waitcnt vmcnt(0)" ::: "memory");           \
        } else {                                                               \
            __asm__ __volatile__("s_waitcnt vmcnt(6)" ::: "memory");           \
        }                                                                      \
        __builtin_amdgcn_s_barrier();                                          \
        __builtin_amdgcn_sched_barrier(0);                                     \
        if (t + 2 < NT) {                                                      \
            bf16* dst = smem + nxt2 * 24576 + tid * 8;                         \
            const size_t ko = (size_t)(t + 2) * 64;                            \
            lds16(pa + ko,           dst);                                     \
            lds16(pa + a64 + ko,     dst + 4096);                              \
            lds16(pa + 2*a64 + ko,   dst + 8192);                              \
            lds16(pa + 3*a64 + ko,   dst + 12288);                             \
            lds16(pb + ko,           dst + 16384);                             \
            lds16(pb + b64 + ko,     dst + 20480);                             \
        }                                                                      \
        const bf16* Ab = smem + cur * 24576;                                   \
        const bf16* Bb = Ab + 16384;                                           \
        bf16x8 af[4][2], bfr[4][2];                                            \
        _Pragma("unroll")                                                      \
        for (int mi = 0; mi < 4; mi++)                                         \
            _Pragma("unroll")                                                  \
            for (int ks = 0; ks < 2; ks++)                                     \
                af[mi][ks] = *(const bf16x8*)&Ab[(wr*64 + mi*16 + l16)*64 +    \
                                                 (((ks<<2)|quad) ^ sw8)*8];    \
        _Pragma("unroll")                                                      \
        for (int ni = 0; ni < 4; ni++)                                         \
            _Pragma("unroll")                                                  \
            for (int ks = 0; ks < 2; ks++)                                     \
                bfr[ni][ks] = *(const bf16x8*)&Bb[(wc*64 + ni*16 + l16)*64 +   \
                                                  (((ks<<2)|quad) ^ sw8)*8];   \
        __builtin_amdgcn_s_setprio(1);                                         \
        _Pragma("unroll")                                                      \
        for (int ks = 0; ks < 2; ks++)                                         \
            _Pragma("unroll")                                                  \
            for (int mi = 0; mi < 4; mi++)                                     \
                _Pragma("unroll")                                              \
                for (int ni = 0; ni < 4; ni++)                                 \
                    acc[mi][ni] = __builtin_amdgcn_mfma_f32_16x16x32_bf16(     \
                        af[mi][ks], bfr[ni][ks], acc[mi][ni], 0, 0, 0);        \
        __builtin_amdgcn_s_setprio(0);                                         \
        cur  = (cur  == 2) ? 0 : cur  + 1;                                     \
        nxt2 = (nxt2 == 2) ? 0 : nxt2 + 1;                                     \
    }

// ---------------------------------------------------------------------------
// Fused Q+C projection: [q | clat] = x @ [Wq | Wc], N=3072. 384 blocks.
// ---------------------------------------------------------------------------
__global__ __launch_bounds__(512, 2) void gemm_qc_250(
    const bf16* __restrict__ A, const bf16* __restrict__ Bt,
    bf16* __restrict__ Cq, bf16* __restrict__ Cc)
{
    const int m0 = blockIdx.y * 256, n0 = blockIdx.x * 128;
    GEMM250_CORE(A, Bt, C_, C_, C_)
    const bool is_q = (n0 < C_);                       // 128 | 2048: uniform
    const float scl = is_q ? 0.08838834764831845f : 1.0f;   // 1/sqrt(128)
    bf16* dst = is_q ? Cq : Cc;
    const int ld   = is_q ? C_ : DL_;
    const int coff = is_q ? 0 : C_;
#pragma unroll
    for (int mi = 0; mi < 4; mi++) {
#pragma unroll
        for (int ni = 0; ni < 4; ni++) {
            const int col = n0 - coff + wc * 64 + ni * 16 + l16;
#pragma unroll
            for (int r = 0; r < 4; r++) {
                const int row = m0 + wr * 64 + mi * 16 + quad * 4 + r;
                dst[(size_t)row * ld + col] = __float2bfloat16(acc[mi][ni][r] * scl);
            }
        }
    }
}

// ---------------------------------------------------------------------------
// Fused K-proj + Vt-proj (both K=1024, both consume clat): 512 blocks.
// ---------------------------------------------------------------------------
__global__ __launch_bounds__(512, 2) void gemm_kv_250(
    const bf16* __restrict__ clat, const bf16* __restrict__ Wk_t,
    const bf16* __restrict__ Wv_t, bf16* __restrict__ kk, bf16* __restrict__ vt)
{
    const int bid = blockIdx.x;
    const bf16 *A, *Bt; bf16* dst; int N, m0, n0;
    if (bid < 256) { A = clat; Bt = Wk_t; dst = kk; N = C_;
                     m0 = (bid >> 4) * 256; n0 = (bid & 15) * 128; }
    else           { const int t2 = bid - 256;
                     A = Wv_t; Bt = clat; dst = vt; N = M_;
                     m0 = (t2 >> 5) * 256; n0 = (t2 & 31) * 128; }
    GEMM250_CORE(A, Bt, DL_, DL_, DL_)
#pragma unroll
    for (int mi = 0; mi < 4; mi++) {
#pragma unroll
        for (int ni = 0; ni < 4; ni++) {
            const int col = n0 + wc * 64 + ni * 16 + l16;
#pragma unroll
            for (int r = 0; r < 4; r++) {
                const int row = m0 + wr * 64 + mi * 16 + quad * 4 + r;
                dst[(size_t)row * N + col] = __float2bfloat16(acc[mi][ni][r]);
            }
        }
    }
}

// ---------------------------------------------------------------------------
// Out-projection: out = y @ Wo_t^T + bo, fp32 out. 256 blocks (one round).
// ---------------------------------------------------------------------------
__global__ __launch_bounds__(512, 2) void gemm_out_250(
    const bf16* __restrict__ A, const bf16* __restrict__ Bt,
    float* __restrict__ Cf32, const float* __restrict__ bias)
{
    const int m0 = blockIdx.y * 256, n0 = blockIdx.x * 128;
    GEMM250_CORE(A, Bt, C_, C_, C_)
#pragma unroll
    for (int mi = 0; mi < 4; mi++) {
#pragma unroll
        for (int ni = 0; ni < 4; ni++) {
            const int col = n0 + wc * 64 + ni * 16 + l16;
#pragma unroll
            for (int r = 0; r < 4; r++) {
                const int row = m0 + wr * 64 + mi * 16 + quad * 4 + r;
                Cf32[(size_t)row * C_ + col] = acc[mi][ni][r] + bias[col];
            }
        }
    }
}

// ---------------------------------------------------------------------------
// Flash attention v3 "sb": single q-tile (64 rows)/block, 256 thr = 4 waves,
// grid 1024, LPT (longest blocks first). K and V SINGLE-buffered in LDS with
// OFFSET staging:
//   K(j+1) overwrites Ks right after the post-QK barrier (reads done);
//   V(j+1) overwrites Vs right after the post-PV barrier.
// All waits counted (vmcnt(4)); only last iter's V-wait is vmcnt(0).
// LDS = Ks 16K + Vs 16K + Ps 9K = 41.6 KB -> 3 blocks/CU, 12 waves/CU
// (1.5x TLP of flash_dual). V loads never share a hot vmcnt window with K
// (R5 lesson: V-direct poisoned the counter).
// Numerics bitwise-identical to flash_dual (same accumulation order).
// ---------------------------------------------------------------------------
__global__ __launch_bounds__(256, 3) void flash_sb(
    const bf16* __restrict__ Q, const bf16* __restrict__ K,
    const bf16* __restrict__ Vt, bf16* __restrict__ Y)
{
    __shared__ __align__(16) bf16 Ks[4][64][32];       // 16 KB (single buf)
    __shared__ __align__(16) bf16 Vs[2][128][32];      // 16 KB (single buf)
    __shared__ __align__(16) bf16 Ps[4][16][72];       // 9 KB (+8 pad)
    const int tid  = threadIdx.x;
    const int lane = tid & 63, wv = tid >> 6;          // wv 0..3
    const int quad = lane >> 4, l16 = lane & 15;
    const int sw = (l16 >> 1) & 3;
    const int bid = blockIdx.x;
    const int bh = (bid & 7) * 4 + ((bid >> 3) & 3);   // XCD-local (b,h)
    const int pa = (NT64_ - 1) - (bid >> 5);           // LPT: longest first
    const int b = bh >> 4, h = bh & 15;
    const int q0 = pa * 64;
    const int nj = pa + 1;                             // kv tiles (causal)
    const int rb = q0 + wv * 16;                       // wave's row base

    // staging: 256 threads cover 16 KB -> 4 lds16 each (per K or V tile)
    const int sr  = tid >> 2;                          // row 0..63
    const int ssl = ((tid & 3) ^ ((sr >> 1) & 3)) * 8; // swizzled 16B slot

    // Q fragments: wave rows q0 + wv*16 + l16, 4 k-chunks
    bf16x8 qf[4];
    {
        const size_t rQ = (size_t)(b * T_ + q0 + wv * 16 + l16) * C_ + h * HS_;
#pragma unroll
        for (int c = 0; c < 4; c++)
            qf[c] = *(const bf16x8*)(Q + rQ + c * 32 + quad * 8);
    }

    f32x4 o[8];
#pragma unroll
    for (int dt = 0; dt < 8; dt++) o[dt] = (f32x4){0.f, 0.f, 0.f, 0.f};
    float l_s[4] = {0.f, 0.f, 0.f, 0.f};

    auto stageK = [&](int j) {
        const int kv0 = j * 64;
#pragma unroll
        for (int kc = 0; kc < 4; kc++)
            lds16(K + (size_t)(b * T_ + kv0 + sr) * C_ + h * HS_ + kc * 32 + ssl,
                  &Ks[kc][0][0] + tid * 8);
    };
    auto stageV = [&](int j) {
        const int kv0 = j * 64;
#pragma unroll
        for (int vc = 0; vc < 2; vc++)
#pragma unroll
            for (int hf = 0; hf < 2; hf++)
                lds16(Vt + (size_t)(h * HS_ + hf * 64 + sr) * M_ + b * T_ + kv0 + vc * 32 + ssl,
                      &Vs[vc][hf * 64][0] + tid * 8);
    };

    // softmax + Ps store for one 32-kv half (nt0 in {0,2}); returns PV A-frag.
    auto sm_half = [&](const f32x4* s, int nt0, bool diag, int kv0) {
        float p[2][4];
#pragma unroll
        for (int t = 0; t < 2; t++)
#pragma unroll
            for (int r = 0; r < 4; r++) {
                const int nt = nt0 + t;
                float e = __expf(s[nt][r]);
                if (diag) {
                    const int col = kv0 + nt * 16 + l16;
                    const int row = rb + quad * 4 + r;
                    if (col > row) e = 0.f;
                }
                p[t][r] = e;
            }
#pragma unroll
        for (int r = 0; r < 4; r++) l_s[r] += p[0][r] + p[1][r];
#pragma unroll
        for (int t = 0; t < 2; t++)
#pragma unroll
            for (int r = 0; r < 4; r++)
                Ps[wv][quad * 4 + r][(nt0 + t) * 16 + l16] = __float2bfloat16(p[t][r]);
        return *(const bf16x8*)&Ps[wv][l16][nt0 * 16 + quad * 8];
    };

    stageK(0);                                         // 4 loads
    stageV(0);                                         // 4 loads
    for (int j = 0; j < nj; j++) {
        const int kv0 = j * 64;
        const bool more = (j + 1 < nj);

        // ---- entry: K(j) landed (V(j) may be in flight) ----
        __asm__ __volatile__("s_waitcnt vmcnt(4)" ::: "memory");
        __builtin_amdgcn_s_barrier();                  // Ks(j) visible to all
        __builtin_amdgcn_sched_barrier(0);

        // ---- QK^T ----
        f32x4 s[4];
#pragma unroll
        for (int nt = 0; nt < 4; nt++) s[nt] = (f32x4){0.f, 0.f, 0.f, 0.f};
        __builtin_amdgcn_s_setprio(1);
#pragma unroll
        for (int c = 0; c < 4; c++) {
            bf16x8 kf[4];
#pragma unroll
            for (int nt = 0; nt < 4; nt++)
                kf[nt] = *(const bf16x8*)&Ks[c][nt * 16 + l16][(quad ^ sw) * 8];
#pragma unroll
            for (int nt = 0; nt < 4; nt++)
                s[nt] = __builtin_amdgcn_mfma_f32_16x16x32_bf16(qf[c], kf[nt], s[nt], 0, 0, 0);
        }
        __builtin_amdgcn_s_setprio(0);

        __asm__ __volatile__("s_waitcnt lgkmcnt(0)" ::: "memory");
        __builtin_amdgcn_s_barrier();                  // all Ks(j) reads done
        __builtin_amdgcn_sched_barrier(0);
        if (more) stageK(j + 1);                       // safe overwrite of Ks

        // ---- softmax (overlaps K(j+1) flight) ----
        const bool dg = (j == nj - 1);
        const bf16x8 p0 = sm_half(s, 0, dg, kv0);
        const bf16x8 p1 = sm_half(s, 2, dg, kv0);

        // ---- V(j) landed (K(j+1) is the allowed 4 in flight) ----
        if (more) {
            __asm__ __volatile__("s_waitcnt vmcnt(4)" ::: "memory");
        } else {
            __asm__ __volatile__("s_waitcnt vmcnt(0)" ::: "memory");
        }
        __builtin_amdgcn_s_barrier();                  // Vs(j) visible to all
        __builtin_amdgcn_sched_barrier(0);

        // ---- PV ----
        __builtin_amdgcn_s_setprio(1);
#pragma unroll
        for (int dt = 0; dt < 8; dt++) {
            const bf16x8 vf0 = *(const bf16x8*)&Vs[0][dt * 16 + l16][(quad ^ sw) * 8];
            o[dt] = __builtin_amdgcn_mfma_f32_16x16x32_bf16(p0, vf0, o[dt], 0, 0, 0);
        }
#pragma unroll
        for (int dt = 0; dt < 8; dt++) {
            const bf16x8 vf1 = *(const bf16x8*)&Vs[1][dt * 16 + l16][(quad ^ sw) * 8];
            o[dt] = __builtin_amdgcn_mfma_f32_16x16x32_bf16(p1, vf1, o[dt], 0, 0, 0);
        }
        __builtin_amdgcn_s_setprio(0);

        __asm__ __volatile__("s_waitcnt lgkmcnt(0)" ::: "memory");
        __builtin_amdgcn_s_barrier();                  // all Vs(j) reads done
        __builtin_amdgcn_sched_barrier(0);
        if (more) stageV(j + 1);                       // safe overwrite of Vs
    }

    // ---- epilogue: reduce l across 16-lane col group, normalize, store
    {
        float inv[4];
#pragma unroll
        for (int r = 0; r < 4; r++) {
            float l = l_s[r];
            l += __shfl_xor(l, 1);
            l += __shfl_xor(l, 2);
            l += __shfl_xor(l, 4);
            l += __shfl_xor(l, 8);
            inv[r] = 1.f / l;
        }
#pragma unroll
        for (int dt = 0; dt < 8; dt++)
#pragma unroll
            for (int r = 0; r < 4; r++)
                Y[(size_t)(b * T_ + rb + quad * 4 + r) * C_ + h * HS_ + dt * 16 + l16] =
                    __float2bfloat16(o[dt][r] * inv[r]);
    }
}

// ---------------------------------------------------------------------------
extern "C" void kernel_launch(void* const* d_in, const int* in_sizes, int n_in,
                              void* d_out, int out_size, void* d_ws, size_t ws_size,
                              hipStream_t stream) {
    const float* x  = (const float*)d_in[0];
    const float* Wq = (const float*)d_in[1];
    const float* Wc = (const float*)d_in[2];
    const float* Wk = (const float*)d_in[3];
    const float* Wv = (const float*)d_in[4];
    const float* Wo = (const float*)d_in[5];
    const float* bo = (const float*)d_in[6];
    float* out = (float*)d_out;

    bf16* ws   = (bf16*)d_ws;
    bf16* x_bf = ws;                            // (M,C)
    bf16* Wq_t = x_bf + (size_t)M_ * C_;        // (C,C)   contiguous with Wc_t
    bf16* Wc_t = Wq_t + (size_t)C_ * C_;        // (DL,C)
    bf16* Wk_t = Wc_t + (size_t)DL_ * C_;       // (C,DL)
    bf16* Wv_t = Wk_t + (size_t)C_ * DL_;       // (C,DL)
    bf16* Wo_t = Wv_t + (size_t)C_ * DL_;       // (C,C)
    bf16* q    = Wo_t + (size_t)C_ * C_;        // (M,C)  pre-scaled by 1/sqrt(HS)
    bf16* clat = q    + (size_t)M_ * C_;        // (M,DL)
    bf16* kk   = clat + (size_t)M_ * DL_;       // (M,C)
    bf16* vt   = kk   + (size_t)M_ * C_;        // (C,M)  V transposed
    bf16* y    = vt   + (size_t)C_ * M_;        // (M,C)

    const dim3 blk(256);
    const dim3 blk512(512);

    cast_bf16_k<<<dim3((M_ * C_) / (256 * 8)), blk, 0, stream>>>(x, x_bf);
    transpose_cast5<<<dim3(C_ / 32, C_ / 32, 5), blk, 0, stream>>>(
        Wq, Wc, Wk, Wv, Wo, Wq_t, Wc_t, Wk_t, Wv_t, Wo_t);

    // fused [q | clat] projection: Bt = [Wq_t ; Wc_t] (3072 x 2048)
    gemm_qc_250<<<dim3((C_ + DL_) / 128, M_ / 256), blk512, 0, stream>>>(
        x_bf, Wq_t, q, clat);
    // fused K-proj + Vt-proj (512 blocks, both K=1024)
    gemm_kv_250<<<dim3(512), blk512, 0, stream>>>(clat, Wk_t, Wv_t, kk, vt);

    flash_sb<<<dim3(NT64_ * H_ * B_), blk, 0, stream>>>(q, kk, vt, y);

    gemm_out_250<<<dim3(C_ / 128, M_ / 256), blk512, 0, stream>>>(
        y, Wo_t, out, bo);
}